// Round 1
// baseline (1450.961 us; speedup 1.0000x reference)
//
#include <hip/hip_runtime.h>
#include <stdint.h>

#define B_ 4
#define T_ 2048
#define H_ 1024
#define S_ 512
#define R_ 16
#define E_ 4
#define F_ 38
#define BT_ (B_*T_)
#define KF_ 320   // padded 2*E*F = 304 -> 320

typedef __attribute__((ext_vector_type(8))) __bf16 bf16x8;
typedef __attribute__((ext_vector_type(4))) float f32x4;

static __device__ __forceinline__ float bf2f(unsigned short u) {
    return __uint_as_float(((unsigned int)u) << 16);
}
static __device__ __forceinline__ unsigned short f2bf(float f) {
    unsigned int u = __float_as_uint(f);
    unsigned int r = (u + 0x7fffu + ((u >> 16) & 1u)) >> 16;
    return (unsigned short)r;
}

// ---------------- bf16 MFMA GEMM: C[M,N] (fp32) = A[M,K] @ BT[N,K]^T + bias ----------------
// 128x128 tile, 4 waves (2x2), each wave 64x64 = 4x4 MFMA 16x16x32 subtiles. K % 32 == 0.
__global__ __launch_bounds__(256) void k_gemm(
    const unsigned short* __restrict__ A, int lda,
    const unsigned short* __restrict__ BT, int ldb,
    float* __restrict__ C, int ldc,
    const float* __restrict__ bias, int K)
{
    __shared__ unsigned short As[128 * 32];
    __shared__ unsigned short Bs[128 * 32];
    const int tid = threadIdx.x;
    const int l = tid & 63;
    const int w = tid >> 6;
    const int wm = w >> 1, wn = w & 1;
    const int m16 = l & 15, kg = l >> 4;
    const size_t bm = (size_t)blockIdx.y * 128;
    const size_t bn = (size_t)blockIdx.x * 128;

    const int rS = tid >> 2;
    const int kS = (tid & 3) * 8;
    const unsigned short* pA0 = A + (bm + rS) * (size_t)lda + kS;
    const unsigned short* pA1 = pA0 + (size_t)64 * lda;
    const unsigned short* pB0 = BT + (bn + rS) * (size_t)ldb + kS;
    const unsigned short* pB1 = pB0 + (size_t)64 * ldb;

    f32x4 acc[4][4];
#pragma unroll
    for (int i = 0; i < 4; ++i)
#pragma unroll
        for (int j = 0; j < 4; ++j) acc[i][j] = (f32x4){0.f, 0.f, 0.f, 0.f};

    uint4 ra0 = *(const uint4*)pA0;
    uint4 ra1 = *(const uint4*)pA1;
    uint4 rb0 = *(const uint4*)pB0;
    uint4 rb1 = *(const uint4*)pB1;

    const int s0 = tid * 8;
    const int s1 = (256 + tid) * 8;
    const int nkt = K >> 5;
    for (int kt = 0; kt < nkt; ++kt) {
        __syncthreads();
        *(uint4*)&As[s0] = ra0;
        *(uint4*)&As[s1] = ra1;
        *(uint4*)&Bs[s0] = rb0;
        *(uint4*)&Bs[s1] = rb1;
        if (kt + 1 < nkt) {
            pA0 += 32; pA1 += 32; pB0 += 32; pB1 += 32;
            ra0 = *(const uint4*)pA0;
            ra1 = *(const uint4*)pA1;
            rb0 = *(const uint4*)pB0;
            rb1 = *(const uint4*)pB1;
        }
        __syncthreads();
        bf16x8 af[4], bfr[4];
#pragma unroll
        for (int i = 0; i < 4; ++i)
            af[i] = *(const bf16x8*)&As[(wm * 64 + i * 16 + m16) * 32 + kg * 8];
#pragma unroll
        for (int j = 0; j < 4; ++j)
            bfr[j] = *(const bf16x8*)&Bs[(wn * 64 + j * 16 + m16) * 32 + kg * 8];
#pragma unroll
        for (int i = 0; i < 4; ++i)
#pragma unroll
            for (int j = 0; j < 4; ++j)
                acc[i][j] = __builtin_amdgcn_mfma_f32_16x16x32_bf16(af[i], bfr[j], acc[i][j], 0, 0, 0);
    }

#pragma unroll
    for (int j = 0; j < 4; ++j) {
        const size_t col = bn + wn * 64 + j * 16 + m16;
        const float bv = bias ? bias[col] : 0.f;
#pragma unroll
        for (int i = 0; i < 4; ++i) {
            const size_t row0 = bm + wm * 64 + i * 16 + kg * 4;
#pragma unroll
            for (int p = 0; p < 4; ++p)
                C[(row0 + p) * (size_t)ldc + col] = acc[i][j][p] + bv;
        }
    }
}

// ---------------- cast x -> bf16 into Abig cols [0,1024) ----------------
__global__ __launch_bounds__(256) void k_cast_x(const float* __restrict__ x,
                                                unsigned short* __restrict__ Abig)
{
    const int gid = blockIdx.x * 256 + threadIdx.x;   // BT_*H_/4
    const int row = gid >> 8;
    const int c4 = (gid & 255) << 2;
    float4 v = *(const float4*)&x[(size_t)row * H_ + c4];
    ushort4 o;
    o.x = f2bf(v.x); o.y = f2bf(v.y); o.z = f2bf(v.z); o.w = f2bf(v.w);
    *(ushort4*)&Abig[(size_t)row * 4096 + c4] = o;
}

// ---------------- transpose-cast g_W [4096,1024] -> gWT bf16 [1024,4096] ----------------
__global__ __launch_bounds__(256) void k_gwt(const float* __restrict__ gW,
                                             unsigned short* __restrict__ gWT)
{
    __shared__ float tile[32][33];
    const int tx = threadIdx.x & 31, ty = threadIdx.x >> 5;   // ty 0..7
    const int k0 = blockIdx.x * 32, n0 = blockIdx.y * 32;
#pragma unroll
    for (int q = 0; q < 4; ++q) {
        int kk = ty * 4 + q;
        tile[kk][tx] = gW[(size_t)(k0 + kk) * H_ + n0 + tx];
    }
    __syncthreads();
#pragma unroll
    for (int q = 0; q < 4; ++q) {
        int nn = ty * 4 + q;
        gWT[(size_t)(n0 + nn) * 4096 + k0 + tx] = f2bf(tile[tx][nn]);
    }
}

// ---------------- WuT[n,h] = composed sigma->A weights, bf16 [128,1024] ----------------
__global__ __launch_bounds__(64) void k_wu(const float* __restrict__ sigWr,
                                           const float* __restrict__ sigWi,
                                           const float* __restrict__ A_r,
                                           const float* __restrict__ A_i,
                                           unsigned short* __restrict__ WuT)
{
    __shared__ float swr[S_], swi[S_];
    const int h = blockIdx.x;
    const int tid = threadIdx.x;
    for (int s = tid; s < S_; s += 64) {
        swr[s] = sigWr[(size_t)h * S_ + s];
        swi[s] = sigWi[(size_t)h * S_ + s];
    }
    __syncthreads();
    const int e = tid >> 4, r = tid & 15;
    float a0 = 0.f, a1 = 0.f;
    for (int s = 0; s < S_; ++s) {
        float ar = A_r[((size_t)(e * S_ + s)) * R_ + r];
        float ai = A_i[((size_t)(e * S_ + s)) * R_ + r];
        float wr = swr[s], wi = swi[s];
        a0 += wr * ar - wi * ai;
        a1 += wr * ai + wi * ar;
    }
    WuT[(size_t)tid * H_ + h] = f2bf(a0);
    WuT[(size_t)(64 + tid) * H_ + h] = f2bf(a1);
}

// ---------------- b_u[128] ----------------
__global__ __launch_bounds__(128) void k_bu(const float* __restrict__ sigbr,
                                            const float* __restrict__ sigbi,
                                            const float* __restrict__ A_r,
                                            const float* __restrict__ A_i,
                                            float* __restrict__ b_u)
{
    const int n = threadIdx.x;
    float acc = 0.f;
    if (n < 64) {
        const int e = n >> 4, r = n & 15;
        for (int s = 0; s < S_; ++s)
            acc += sigbr[s] * A_r[((size_t)(e * S_ + s)) * R_ + r]
                 - sigbi[s] * A_i[((size_t)(e * S_ + s)) * R_ + r];
    } else {
        const int m = n - 64;
        const int e = m >> 4, r = m & 15;
        for (int s = 0; s < S_; ++s)
            acc += sigbr[s] * A_i[((size_t)(e * S_ + s)) * R_ + r]
                 + sigbi[s] * A_r[((size_t)(e * S_ + s)) * R_ + r];
    }
    b_u[n] = acc;
}

// ---------------- b2 init: b2[0:1024)=fu_br, [1024:2048)=fu_bi ----------------
__global__ __launch_bounds__(256) void k_b2init(const float* __restrict__ fubr,
                                                const float* __restrict__ fubi,
                                                float* __restrict__ b2)
{
    const int h = blockIdx.x * 256 + threadIdx.x;
    b2[h] = (h < H_) ? fubr[h] : fubi[h - H_];
}

// ---------------- compose M = eh_W (x) fu_W per engine; also eh-bias into b2 ----------------
__global__ __launch_bounds__(256) void k_mcompose(
    const float* __restrict__ ehWr, const float* __restrict__ ehWi,
    const float* __restrict__ ehbr, const float* __restrict__ ehbi,
    const float* __restrict__ fuWr, const float* __restrict__ fuWi,
    float* __restrict__ Mr, float* __restrict__ Mi, float* __restrict__ b2)
{
    const int bx = blockIdx.x;               // 256 blocks
    const int e = bx & 3;
    const int ht = (bx >> 2) & 15;
    const int ks = bx >> 6;                  // 0..3
    const int col = threadIdx.x & 63;
    const int h = ht * 64 + col;
    const int fg = threadIdx.x >> 6;         // 0..3
    float aR[10], aI[10];
#pragma unroll
    for (int s = 0; s < 10; ++s) { aR[s] = 0.f; aI[s] = 0.f; }
    float bR = 0.f, bI = 0.f;
    const int k0 = ks * 256;
    for (int k = k0; k < k0 + 256; ++k) {
        const float fur = fuWr[((size_t)(e * H_ + k)) * H_ + h];
        const float fui = fuWi[((size_t)(e * H_ + k)) * H_ + h];
#pragma unroll
        for (int s = 0; s < 10; ++s) {
            const int f = fg + 4 * s;
            if (f < F_) {
                const float er = ehWr[((size_t)(e * F_ + f)) * H_ + k];
                const float ei = ehWi[((size_t)(e * F_ + f)) * H_ + k];
                aR[s] += er * fur - ei * fui;
                aI[s] += er * fui + ei * fur;
            }
        }
        if (fg == 0) {
            const float br = ehbr[e * H_ + k], bi = ehbi[e * H_ + k];
            bR += br * fur - bi * fui;
            bI += br * fui + bi * fur;
        }
    }
#pragma unroll
    for (int s = 0; s < 10; ++s) {
        const int f = fg + 4 * s;
        if (f < F_) {
            atomicAdd(&Mr[(size_t)(e * F_ + f) * H_ + h], aR[s]);
            atomicAdd(&Mi[(size_t)(e * F_ + f) * H_ + h], aI[s]);
        }
    }
    if (fg == 0) {
        atomicAdd(&b2[h], bR);
        atomicAdd(&b2[H_ + h], bI);
    }
}

// ---------------- pack W2T bf16 [2048, KF_] from Mr/Mi ----------------
__global__ __launch_bounds__(256) void k_w2t(const float* __restrict__ Mr,
                                             const float* __restrict__ Mi,
                                             unsigned short* __restrict__ W2T)
{
    const int gid = blockIdx.x * 256 + threadIdx.x;  // 2048*KF_
    const int n = gid / KF_;
    const int k = gid - n * KF_;
    const int nn = n & (H_ - 1);
    const bool hi = n >= H_;
    float v = 0.f;
    if (k < 152)       v = hi ? Mi[(size_t)k * H_ + nn] : Mr[(size_t)k * H_ + nn];
    else if (k < 304) { const int kk = k - 152;
                        v = hi ? Mr[(size_t)kk * H_ + nn] : -Mi[(size_t)kk * H_ + nn]; }
    W2T[gid] = f2bf(v);
}

// ---------------- sequential complex recurrence over T ----------------
__global__ __launch_bounds__(64) void k_scan(const float* __restrict__ U,
                                             const float* __restrict__ lam_r,
                                             const float* __restrict__ lam_i,
                                             float* __restrict__ Hr, float* __restrict__ Hi)
{
    const int b = blockIdx.x;
    const int tid = threadIdx.x;                 // = e*16+r
    const float cr = 0.9f * lam_r[tid];
    const float ci = 0.9f * lam_i[tid];
    const float* Ub = U + (size_t)b * T_ * 128;
    float* HrB = Hr + (size_t)b * T_ * 64;
    float* HiB = Hi + (size_t)b * T_ * 64;
    float hr = 0.f, hi = 0.f;
    float pr[8], pi[8];
#pragma unroll
    for (int j = 0; j < 8; ++j) { pr[j] = Ub[j * 128 + tid]; pi[j] = Ub[j * 128 + 64 + tid]; }
    for (int t0 = 0; t0 < T_; t0 += 8) {
        float qr[8], qi[8];
#pragma unroll
        for (int j = 0; j < 8; ++j) { qr[j] = pr[j]; qi[j] = pi[j]; }
        if (t0 + 8 < T_) {
#pragma unroll
            for (int j = 0; j < 8; ++j) {
                pr[j] = Ub[(t0 + 8 + j) * 128 + tid];
                pi[j] = Ub[(t0 + 8 + j) * 128 + 64 + tid];
            }
        }
#pragma unroll
        for (int j = 0; j < 8; ++j) {
            float nr = fmaf(cr, hr, fmaf(-ci, hi, 0.1f * qr[j]));
            float ni = fmaf(cr, hi, fmaf(ci, hr, 0.1f * qi[j]));
            HrB[(t0 + j) * 64 + tid] = nr;
            HiB[(t0 + j) * 64 + tid] = ni;
            hr = nr; hi = ni;
        }
    }
}

// ---------------- per-(e,b,t) features (parallel) ----------------
__global__ __launch_bounds__(256) void k_feat(const float* __restrict__ Hr,
                                              const float* __restrict__ Hi,
                                              unsigned short* __restrict__ Fcat,
                                              float* __restrict__ Mbuf)
{
    const int gid = blockIdx.x * 256 + threadIdx.x;  // 32768
    const int e = gid & 3;
    const int bt = gid >> 2;
    const float* hr = Hr + (size_t)bt * 64 + e * 16;
    const float* hi = Hi + (size_t)bt * 64 + e * 16;
    float nr[16], ni[16];
#pragma unroll
    for (int q = 0; q < 4; ++q) {
        float4 vr = ((const float4*)hr)[q];
        float4 vi = ((const float4*)hi)[q];
        nr[q*4+0]=vr.x; nr[q*4+1]=vr.y; nr[q*4+2]=vr.z; nr[q*4+3]=vr.w;
        ni[q*4+0]=vi.x; ni[q*4+1]=vi.y; ni[q*4+2]=vi.z; ni[q*4+3]=vi.w;
    }
    float sum = 0.f, mx = 0.f, sr = 0.f, si = 0.f;
#pragma unroll
    for (int i = 0; i < 16; ++i) {
        float m2 = nr[i] * nr[i] + ni[i] * ni[i];
        sum += m2; mx = fmaxf(mx, m2);
        sr += nr[i]; si += ni[i];
    }
    const float mm = sum * 0.0625f;
    const float inv = rsqrtf(mm + 1e-6f);
    const int b = bt >> 11, t = bt & (T_ - 1);
    Mbuf[(size_t)(e * 4 + b) * T_ + t] = mm;
    unsigned short* Fp = Fcat + (size_t)bt * KF_;
    const int br = e * F_, bi2 = 152 + e * F_;
    const float mhr = sr * 0.0625f * inv;
    const float mhi = si * 0.0625f * inv;
    Fp[br + 0] = f2bf(mhr);
    Fp[br + 1] = f2bf(mhi);
    Fp[br + 2] = f2bf(sqrtf(mm + 1e-6f));
    Fp[br + 3] = f2bf(sqrtf(mx + 1e-6f));
    Fp[bi2 + 0] = f2bf(mhi);
    Fp[bi2 + 1] = f2bf(-mhr);
#pragma unroll
    for (int i = 0; i < 16; ++i) {
        float a = nr[i] * inv, c = ni[i] * inv;
        Fp[br + 6 + i]   = f2bf(a);
        Fp[br + 22 + i]  = f2bf(c);
        Fp[bi2 + 6 + i]  = f2bf(c);
        Fp[bi2 + 22 + i] = f2bf(-a);
    }
}

// ---------------- acc recurrence (16 sequences) ----------------
__global__ __launch_bounds__(64) void k_acc(const float* __restrict__ Mbuf,
                                            unsigned short* __restrict__ Fcat)
{
    const int tid = threadIdx.x;
    if (tid >= 16) return;
    const int e = tid >> 2, b = tid & 3;
    const float* mp = Mbuf + (size_t)(e * 4 + b) * T_;
    float acc = 0.f;
    for (int t = 0; t < T_; ++t) {
        acc = fmaf(0.99f, acc, 0.01f * mp[t]);
        size_t ro = ((size_t)(b * T_ + t)) * KF_ + e * F_;
        Fcat[ro + 4] = f2bf(acc);
        Fcat[ro + 5] = f2bf(log1pf(acc));
    }
}

// ---------------- mag + bf16 frf/fif into Abig ----------------
__global__ __launch_bounds__(256) void k_mag(const float* __restrict__ FRF,
                                             unsigned short* __restrict__ Abig)
{
    const int gid = blockIdx.x * 256 + threadIdx.x;  // BT_*H_
    const int row = gid >> 10;
    const int h = gid & (H_ - 1);
    const float fr = FRF[(size_t)row * 2048 + h];
    const float fi = FRF[(size_t)row * 2048 + 1024 + h];
    const size_t base = (size_t)row * 4096;
    Abig[base + 1024 + h] = f2bf(fr);
    Abig[base + 2048 + h] = f2bf(fi);
    Abig[base + 3072 + h] = f2bf(sqrtf(fr * fr + fi * fi + 1e-6f));
}

// ---------------- final gate + combine ----------------
__global__ __launch_bounds__(256) void k_final(const float* __restrict__ preact,
                                               const float* __restrict__ gb,
                                               const float* __restrict__ FRF,
                                               const float* __restrict__ x,
                                               float* __restrict__ out)
{
    const int gid = blockIdx.x * 256 + threadIdx.x;  // BT_*H_
    const int h = gid & (H_ - 1);
    const int row = gid >> 10;
    const float z = preact[gid] + gb[h];
    const float g = 1.f / (1.f + __expf(-z));
    const float fr = FRF[(size_t)row * 2048 + h];
    out[gid] = g * fr + (1.f - g) * x[gid];
}

extern "C" void kernel_launch(void* const* d_in, const int* in_sizes, int n_in,
                              void* d_out, int out_size, void* d_ws, size_t ws_size,
                              hipStream_t stream)
{
    const float* x     = (const float*)d_in[0];
    const float* sigWr = (const float*)d_in[1];
    const float* sigWi = (const float*)d_in[2];
    const float* sigbr = (const float*)d_in[3];
    const float* sigbi = (const float*)d_in[4];
    const float* A_r   = (const float*)d_in[5];
    const float* A_i   = (const float*)d_in[6];
    const float* lam_r = (const float*)d_in[7];
    const float* lam_i = (const float*)d_in[8];
    const float* ehWr  = (const float*)d_in[9];
    const float* ehWi  = (const float*)d_in[10];
    const float* ehbr  = (const float*)d_in[11];
    const float* ehbi  = (const float*)d_in[12];
    const float* fuWr  = (const float*)d_in[13];
    const float* fuWi  = (const float*)d_in[14];
    const float* fubr  = (const float*)d_in[15];
    const float* fubi  = (const float*)d_in[16];
    const float* gW    = (const float*)d_in[17];
    const float* gb    = (const float*)d_in[18];

    char* ws = (char*)d_ws;
    size_t off = 0;
    auto alloc = [&](size_t bytes) -> void* {
        void* p = ws + off;
        off = (off + bytes + 255) & ~(size_t)255;
        return p;
    };
    unsigned short* Abig = (unsigned short*)alloc((size_t)BT_ * 4096 * 2);
    float* FRF           = (float*)alloc((size_t)BT_ * 2048 * 4);
    unsigned short* Fcat = (unsigned short*)alloc((size_t)BT_ * KF_ * 2);
    float* U             = (float*)alloc((size_t)BT_ * 128 * 4);
    float* Hr            = (float*)alloc((size_t)BT_ * 64 * 4);
    float* Hi            = (float*)alloc((size_t)BT_ * 64 * 4);
    float* Mbuf          = (float*)alloc((size_t)16 * T_ * 4);
    float* preact        = (float*)alloc((size_t)BT_ * H_ * 4);
    unsigned short* WuT  = (unsigned short*)alloc((size_t)128 * H_ * 2);
    float* b_u           = (float*)alloc(128 * 4);
    float* Mr            = (float*)alloc((size_t)152 * H_ * 4);
    float* Mi            = (float*)alloc((size_t)152 * H_ * 4);
    unsigned short* W2T  = (unsigned short*)alloc((size_t)2048 * KF_ * 2);
    float* b2            = (float*)alloc(2048 * 4);
    unsigned short* gWT  = (unsigned short*)alloc((size_t)H_ * 4096 * 2);
    if (off > ws_size) return;   // workspace too small; fail loudly (output stays poisoned)

    hipMemsetAsync(Fcat, 0, (size_t)BT_ * KF_ * 2, stream);
    hipMemsetAsync(Mr, 0, (size_t)2 * 152 * H_ * 4, stream);   // Mr and Mi contiguous

    k_cast_x<<<dim3(BT_ * H_ / 4 / 256), dim3(256), 0, stream>>>(x, Abig);
    k_gwt<<<dim3(128, 32), dim3(256), 0, stream>>>(gW, gWT);
    k_wu<<<dim3(H_), dim3(64), 0, stream>>>(sigWr, sigWi, A_r, A_i, WuT);
    k_bu<<<dim3(1), dim3(128), 0, stream>>>(sigbr, sigbi, A_r, A_i, b_u);
    k_b2init<<<dim3(8), dim3(256), 0, stream>>>(fubr, fubi, b2);
    k_mcompose<<<dim3(256), dim3(256), 0, stream>>>(ehWr, ehWi, ehbr, ehbi, fuWr, fuWi, Mr, Mi, b2);
    k_w2t<<<dim3(2048 * KF_ / 256), dim3(256), 0, stream>>>(Mr, Mi, W2T);

    // u = x @ WuT^T + b_u   [8192,1024]x[1024,128]
    k_gemm<<<dim3(1, 64), dim3(256), 0, stream>>>(Abig, 4096, WuT, H_, U, 128, b_u, H_);

    k_scan<<<dim3(B_), dim3(64), 0, stream>>>(U, lam_r, lam_i, Hr, Hi);
    k_feat<<<dim3(BT_ * E_ / 256), dim3(256), 0, stream>>>(Hr, Hi, Fcat, Mbuf);
    k_acc<<<dim3(1), dim3(64), 0, stream>>>(Mbuf, Fcat);

    // (frf|fif) = Fcat @ W2T^T + b2   [8192,320]x[320,2048]
    k_gemm<<<dim3(16, 64), dim3(256), 0, stream>>>(Fcat, KF_, W2T, KF_, FRF, 2048, b2, KF_);

    k_mag<<<dim3(BT_ * H_ / 256), dim3(256), 0, stream>>>(FRF, Abig);

    // preact = [x|frf|fif|mag] @ gWT^T   [8192,4096]x[4096,1024]
    k_gemm<<<dim3(8, 64), dim3(256), 0, stream>>>(Abig, 4096, gWT, 4096, preact, H_, (const float*)nullptr, 4096);

    k_final<<<dim3(BT_ * H_ / 256), dim3(256), 0, stream>>>(preact, gb, FRF, x, (float*)d_out);
}

// Round 2
// 548.175 us; speedup vs baseline: 2.6469x; 2.6469x over previous
//
#include <hip/hip_runtime.h>
#include <stdint.h>

#define B_ 4
#define T_ 2048
#define H_ 1024
#define S_ 512
#define R_ 16
#define E_ 4
#define F_ 38
#define BT_ (B_*T_)
#define KF_ 320   // padded 2*E*F = 304 -> 320

typedef __attribute__((ext_vector_type(8))) __bf16 bf16x8;
typedef __attribute__((ext_vector_type(4))) float f32x4;

static __device__ __forceinline__ float bf2f(unsigned short u) {
    return __uint_as_float(((unsigned int)u) << 16);
}
static __device__ __forceinline__ unsigned short f2bf(float f) {
    unsigned int u = __float_as_uint(f);
    unsigned int r = (u + 0x7fffu + ((u >> 16) & 1u)) >> 16;
    return (unsigned short)r;
}

// ---------------- bf16 MFMA GEMM: C[M,N] (fp32) = A[M,K] @ BT[N,K]^T + bias ----------------
// 128x128 tile, 4 waves (2x2), each wave 64x64 = 4x4 MFMA 16x16x32 subtiles. K % 32 == 0.
__global__ __launch_bounds__(256) void k_gemm(
    const unsigned short* __restrict__ A, int lda,
    const unsigned short* __restrict__ BT, int ldb,
    float* __restrict__ C, int ldc,
    const float* __restrict__ bias, int K)
{
    __shared__ unsigned short As[128 * 32];
    __shared__ unsigned short Bs[128 * 32];
    const int tid = threadIdx.x;
    const int l = tid & 63;
    const int w = tid >> 6;
    const int wm = w >> 1, wn = w & 1;
    const int m16 = l & 15, kg = l >> 4;
    const size_t bm = (size_t)blockIdx.y * 128;
    const size_t bn = (size_t)blockIdx.x * 128;

    const int rS = tid >> 2;
    const int kS = (tid & 3) * 8;
    const unsigned short* pA0 = A + (bm + rS) * (size_t)lda + kS;
    const unsigned short* pA1 = pA0 + (size_t)64 * lda;
    const unsigned short* pB0 = BT + (bn + rS) * (size_t)ldb + kS;
    const unsigned short* pB1 = pB0 + (size_t)64 * ldb;

    f32x4 acc[4][4];
#pragma unroll
    for (int i = 0; i < 4; ++i)
#pragma unroll
        for (int j = 0; j < 4; ++j) acc[i][j] = (f32x4){0.f, 0.f, 0.f, 0.f};

    uint4 ra0 = *(const uint4*)pA0;
    uint4 ra1 = *(const uint4*)pA1;
    uint4 rb0 = *(const uint4*)pB0;
    uint4 rb1 = *(const uint4*)pB1;

    const int s0 = tid * 8;
    const int s1 = (256 + tid) * 8;
    const int nkt = K >> 5;
    for (int kt = 0; kt < nkt; ++kt) {
        __syncthreads();
        *(uint4*)&As[s0] = ra0;
        *(uint4*)&As[s1] = ra1;
        *(uint4*)&Bs[s0] = rb0;
        *(uint4*)&Bs[s1] = rb1;
        if (kt + 1 < nkt) {
            pA0 += 32; pA1 += 32; pB0 += 32; pB1 += 32;
            ra0 = *(const uint4*)pA0;
            ra1 = *(const uint4*)pA1;
            rb0 = *(const uint4*)pB0;
            rb1 = *(const uint4*)pB1;
        }
        __syncthreads();
        bf16x8 af[4], bfr[4];
#pragma unroll
        for (int i = 0; i < 4; ++i)
            af[i] = *(const bf16x8*)&As[(wm * 64 + i * 16 + m16) * 32 + kg * 8];
#pragma unroll
        for (int j = 0; j < 4; ++j)
            bfr[j] = *(const bf16x8*)&Bs[(wn * 64 + j * 16 + m16) * 32 + kg * 8];
#pragma unroll
        for (int i = 0; i < 4; ++i)
#pragma unroll
            for (int j = 0; j < 4; ++j)
                acc[i][j] = __builtin_amdgcn_mfma_f32_16x16x32_bf16(af[i], bfr[j], acc[i][j], 0, 0, 0);
    }

#pragma unroll
    for (int j = 0; j < 4; ++j) {
        const size_t col = bn + wn * 64 + j * 16 + m16;
        const float bv = bias ? bias[col] : 0.f;
#pragma unroll
        for (int i = 0; i < 4; ++i) {
            const size_t row0 = bm + wm * 64 + i * 16 + kg * 4;
#pragma unroll
            for (int p = 0; p < 4; ++p)
                C[(row0 + p) * (size_t)ldc + col] = acc[i][j][p] + bv;
        }
    }
}

// ---------------- cast x -> bf16 into Abig cols [0,1024) ----------------
__global__ __launch_bounds__(256) void k_cast_x(const float* __restrict__ x,
                                                unsigned short* __restrict__ Abig)
{
    const int gid = blockIdx.x * 256 + threadIdx.x;   // BT_*H_/4
    const int row = gid >> 8;
    const int c4 = (gid & 255) << 2;
    float4 v = *(const float4*)&x[(size_t)row * H_ + c4];
    ushort4 o;
    o.x = f2bf(v.x); o.y = f2bf(v.y); o.z = f2bf(v.z); o.w = f2bf(v.w);
    *(ushort4*)&Abig[(size_t)row * 4096 + c4] = o;
}

// ---------------- transpose-cast g_W [4096,1024] -> gWT bf16 [1024,4096] ----------------
__global__ __launch_bounds__(256) void k_gwt(const float* __restrict__ gW,
                                             unsigned short* __restrict__ gWT)
{
    __shared__ float tile[32][33];
    const int tx = threadIdx.x & 31, ty = threadIdx.x >> 5;   // ty 0..7
    const int k0 = blockIdx.x * 32, n0 = blockIdx.y * 32;
#pragma unroll
    for (int q = 0; q < 4; ++q) {
        int kk = ty * 4 + q;
        tile[kk][tx] = gW[(size_t)(k0 + kk) * H_ + n0 + tx];
    }
    __syncthreads();
#pragma unroll
    for (int q = 0; q < 4; ++q) {
        int nn = ty * 4 + q;
        gWT[(size_t)(n0 + nn) * 4096 + k0 + tx] = f2bf(tile[tx][nn]);
    }
}

// ---------------- WuT[n,h] = composed sigma->A weights, bf16 [128,1024] ----------------
__global__ __launch_bounds__(64) void k_wu(const float* __restrict__ sigWr,
                                           const float* __restrict__ sigWi,
                                           const float* __restrict__ A_r,
                                           const float* __restrict__ A_i,
                                           unsigned short* __restrict__ WuT)
{
    __shared__ float swr[S_], swi[S_];
    const int h = blockIdx.x;
    const int tid = threadIdx.x;
    for (int s = tid; s < S_; s += 64) {
        swr[s] = sigWr[(size_t)h * S_ + s];
        swi[s] = sigWi[(size_t)h * S_ + s];
    }
    __syncthreads();
    const int e = tid >> 4, r = tid & 15;
    float a0 = 0.f, a1 = 0.f;
    for (int s = 0; s < S_; ++s) {
        float ar = A_r[((size_t)(e * S_ + s)) * R_ + r];
        float ai = A_i[((size_t)(e * S_ + s)) * R_ + r];
        float wr = swr[s], wi = swi[s];
        a0 += wr * ar - wi * ai;
        a1 += wr * ai + wi * ar;
    }
    WuT[(size_t)tid * H_ + h] = f2bf(a0);
    WuT[(size_t)(64 + tid) * H_ + h] = f2bf(a1);
}

// ---------------- b_u[128] ----------------
__global__ __launch_bounds__(128) void k_bu(const float* __restrict__ sigbr,
                                            const float* __restrict__ sigbi,
                                            const float* __restrict__ A_r,
                                            const float* __restrict__ A_i,
                                            float* __restrict__ b_u)
{
    const int n = threadIdx.x;
    float acc = 0.f;
    if (n < 64) {
        const int e = n >> 4, r = n & 15;
        for (int s = 0; s < S_; ++s)
            acc += sigbr[s] * A_r[((size_t)(e * S_ + s)) * R_ + r]
                 - sigbi[s] * A_i[((size_t)(e * S_ + s)) * R_ + r];
    } else {
        const int m = n - 64;
        const int e = m >> 4, r = m & 15;
        for (int s = 0; s < S_; ++s)
            acc += sigbr[s] * A_i[((size_t)(e * S_ + s)) * R_ + r]
                 + sigbi[s] * A_r[((size_t)(e * S_ + s)) * R_ + r];
    }
    b_u[n] = acc;
}

// ---------------- b2 init: b2[0:1024)=fu_br, [1024:2048)=fu_bi ----------------
__global__ __launch_bounds__(256) void k_b2init(const float* __restrict__ fubr,
                                                const float* __restrict__ fubi,
                                                float* __restrict__ b2)
{
    const int h = blockIdx.x * 256 + threadIdx.x;
    b2[h] = (h < H_) ? fubr[h] : fubi[h - H_];
}

// ---------------- compose M = eh_W (x) fu_W per engine; also eh-bias into b2 ----------------
__global__ __launch_bounds__(256) void k_mcompose(
    const float* __restrict__ ehWr, const float* __restrict__ ehWi,
    const float* __restrict__ ehbr, const float* __restrict__ ehbi,
    const float* __restrict__ fuWr, const float* __restrict__ fuWi,
    float* __restrict__ Mr, float* __restrict__ Mi, float* __restrict__ b2)
{
    const int bx = blockIdx.x;               // 256 blocks
    const int e = bx & 3;
    const int ht = (bx >> 2) & 15;
    const int ks = bx >> 6;                  // 0..3
    const int col = threadIdx.x & 63;
    const int h = ht * 64 + col;
    const int fg = threadIdx.x >> 6;         // 0..3
    float aR[10], aI[10];
#pragma unroll
    for (int s = 0; s < 10; ++s) { aR[s] = 0.f; aI[s] = 0.f; }
    float bR = 0.f, bI = 0.f;
    const int k0 = ks * 256;
    for (int k = k0; k < k0 + 256; ++k) {
        const float fur = fuWr[((size_t)(e * H_ + k)) * H_ + h];
        const float fui = fuWi[((size_t)(e * H_ + k)) * H_ + h];
#pragma unroll
        for (int s = 0; s < 10; ++s) {
            const int f = fg + 4 * s;
            if (f < F_) {
                const float er = ehWr[((size_t)(e * F_ + f)) * H_ + k];
                const float ei = ehWi[((size_t)(e * F_ + f)) * H_ + k];
                aR[s] += er * fur - ei * fui;
                aI[s] += er * fui + ei * fur;
            }
        }
        if (fg == 0) {
            const float br = ehbr[e * H_ + k], bi = ehbi[e * H_ + k];
            bR += br * fur - bi * fui;
            bI += br * fui + bi * fur;
        }
    }
#pragma unroll
    for (int s = 0; s < 10; ++s) {
        const int f = fg + 4 * s;
        if (f < F_) {
            atomicAdd(&Mr[(size_t)(e * F_ + f) * H_ + h], aR[s]);
            atomicAdd(&Mi[(size_t)(e * F_ + f) * H_ + h], aI[s]);
        }
    }
    if (fg == 0) {
        atomicAdd(&b2[h], bR);
        atomicAdd(&b2[H_ + h], bI);
    }
}

// ---------------- pack W2T bf16 [2048, KF_] from Mr/Mi ----------------
__global__ __launch_bounds__(256) void k_w2t(const float* __restrict__ Mr,
                                             const float* __restrict__ Mi,
                                             unsigned short* __restrict__ W2T)
{
    const int gid = blockIdx.x * 256 + threadIdx.x;  // 2048*KF_
    const int n = gid / KF_;
    const int k = gid - n * KF_;
    const int nn = n & (H_ - 1);
    const bool hi = n >= H_;
    float v = 0.f;
    if (k < 152)       v = hi ? Mi[(size_t)k * H_ + nn] : Mr[(size_t)k * H_ + nn];
    else if (k < 304) { const int kk = k - 152;
                        v = hi ? Mr[(size_t)kk * H_ + nn] : -Mi[(size_t)kk * H_ + nn]; }
    W2T[gid] = f2bf(v);
}

// ---------------- chunk-parallel complex recurrence: one wave per (b,channel) ----------------
// h_t = M h_{t-1} + 0.1 u_t, M = 0.9*lam (uniform per wave). 64 lanes x 32-step chunks,
// Kogge-Stone affine scan over lanes with complex multiplier powers M^(32*2^s).
__global__ __launch_bounds__(64) void k_scan(const float* __restrict__ U,
                                             const float* __restrict__ lam_r,
                                             const float* __restrict__ lam_i,
                                             float* __restrict__ Hr, float* __restrict__ Hi)
{
    const int wid = blockIdx.x;              // 256 = b*64 + ch
    const int b = wid >> 6, ch = wid & 63;
    const int lane = threadIdx.x;
    const float cr = 0.9f * lam_r[ch];
    const float ci = 0.9f * lam_i[ch];
    const float* Ub = U + (size_t)b * T_ * 128;
    const int t0 = lane * 32;
    float ur[32], ui[32];
#pragma unroll
    for (int j = 0; j < 32; ++j) {
        ur[j] = Ub[(size_t)(t0 + j) * 128 + ch];
        ui[j] = Ub[(size_t)(t0 + j) * 128 + 64 + ch];
    }
    // pass A: chunk-local end state from zero init
    float hr = 0.f, hi = 0.f;
#pragma unroll
    for (int j = 0; j < 32; ++j) {
        float nr = fmaf(cr, hr, fmaf(-ci, hi, 0.1f * ur[j]));
        float ni = fmaf(cr, hi, fmaf(ci, hr, 0.1f * ui[j]));
        hr = nr; hi = ni;
    }
    // D = M^32 by 5 squarings
    float dr = cr, di = ci;
#pragma unroll
    for (int q = 0; q < 5; ++q) { float t = dr*dr - di*di; di = 2.f*dr*di; dr = t; }
    // affine inclusive scan: x_l = S_l + D x_{l-1}  (Kogge-Stone, D squares each step)
    float xr = hr, xi = hi;
#pragma unroll
    for (int st = 1; st < 64; st <<= 1) {
        float yr = __shfl_up(xr, (unsigned)st, 64);
        float yi = __shfl_up(xi, (unsigned)st, 64);
        if (lane >= st) {
            float nxr = fmaf(dr, yr, fmaf(-di, yi, xr));
            float nxi = fmaf(dr, yi, fmaf(di, yr, xi));
            xr = nxr; xi = nxi;
        }
        float t = dr*dr - di*di; di = 2.f*dr*di; dr = t;
    }
    // chunk init = exclusive scan = neighbor's inclusive
    float ir = __shfl_up(xr, 1u, 64);
    float ii = __shfl_up(xi, 1u, 64);
    if (lane == 0) { ir = 0.f; ii = 0.f; }
    hr = ir; hi = ii;
    float* HrB = Hr + (size_t)b * T_ * 64;
    float* HiB = Hi + (size_t)b * T_ * 64;
#pragma unroll
    for (int j = 0; j < 32; ++j) {
        float nr = fmaf(cr, hr, fmaf(-ci, hi, 0.1f * ur[j]));
        float ni = fmaf(cr, hi, fmaf(ci, hr, 0.1f * ui[j]));
        HrB[(size_t)(t0 + j) * 64 + ch] = nr;
        HiB[(size_t)(t0 + j) * 64 + ch] = ni;
        hr = nr; hi = ni;
    }
}

// ---------------- per-(e,b,t) features (parallel) ----------------
__global__ __launch_bounds__(256) void k_feat(const float* __restrict__ Hr,
                                              const float* __restrict__ Hi,
                                              unsigned short* __restrict__ Fcat,
                                              float* __restrict__ Mbuf)
{
    const int gid = blockIdx.x * 256 + threadIdx.x;  // 32768
    const int e = gid & 3;
    const int bt = gid >> 2;
    const float* hr = Hr + (size_t)bt * 64 + e * 16;
    const float* hi = Hi + (size_t)bt * 64 + e * 16;
    float nr[16], ni[16];
#pragma unroll
    for (int q = 0; q < 4; ++q) {
        float4 vr = ((const float4*)hr)[q];
        float4 vi = ((const float4*)hi)[q];
        nr[q*4+0]=vr.x; nr[q*4+1]=vr.y; nr[q*4+2]=vr.z; nr[q*4+3]=vr.w;
        ni[q*4+0]=vi.x; ni[q*4+1]=vi.y; ni[q*4+2]=vi.z; ni[q*4+3]=vi.w;
    }
    float sum = 0.f, mx = 0.f, sr = 0.f, si = 0.f;
#pragma unroll
    for (int i = 0; i < 16; ++i) {
        float m2 = nr[i] * nr[i] + ni[i] * ni[i];
        sum += m2; mx = fmaxf(mx, m2);
        sr += nr[i]; si += ni[i];
    }
    const float mm = sum * 0.0625f;
    const float inv = rsqrtf(mm + 1e-6f);
    const int b = bt >> 11, t = bt & (T_ - 1);
    Mbuf[(size_t)(e * 4 + b) * T_ + t] = mm;
    unsigned short* Fp = Fcat + (size_t)bt * KF_;
    const int br = e * F_, bi2 = 152 + e * F_;
    const float mhr = sr * 0.0625f * inv;
    const float mhi = si * 0.0625f * inv;
    Fp[br + 0] = f2bf(mhr);
    Fp[br + 1] = f2bf(mhi);
    Fp[br + 2] = f2bf(sqrtf(mm + 1e-6f));
    Fp[br + 3] = f2bf(sqrtf(mx + 1e-6f));
    Fp[bi2 + 0] = f2bf(mhi);
    Fp[bi2 + 1] = f2bf(-mhr);
#pragma unroll
    for (int i = 0; i < 16; ++i) {
        float a = nr[i] * inv, c = ni[i] * inv;
        Fp[br + 6 + i]   = f2bf(a);
        Fp[br + 22 + i]  = f2bf(c);
        Fp[bi2 + 6 + i]  = f2bf(c);
        Fp[bi2 + 22 + i] = f2bf(-a);
    }
}

// ---------------- acc recurrence: 16 waves, chunk-parallel affine scan ----------------
__global__ __launch_bounds__(256) void k_acc(const float* __restrict__ Mbuf,
                                             unsigned short* __restrict__ Fcat)
{
    const int w = blockIdx.x * 4 + (threadIdx.x >> 6);   // 16 sequences
    const int lane = threadIdx.x & 63;
    const int e = w >> 2, b = w & 3;
    const float* mp = Mbuf + (size_t)(e * 4 + b) * T_ + lane * 32;
    float m[32];
#pragma unroll
    for (int j = 0; j < 32; ++j) m[j] = mp[j];
    // pass A: chunk-local end from zero init
    float s = 0.f;
#pragma unroll
    for (int j = 0; j < 32; ++j) s = fmaf(0.99f, s, 0.01f * m[j]);
    // d = 0.99^32
    float d = 0.99f;
#pragma unroll
    for (int q = 0; q < 5; ++q) d = d * d;
    // Kogge-Stone affine scan
    float x = s;
#pragma unroll
    for (int st = 1; st < 64; st <<= 1) {
        float y = __shfl_up(x, (unsigned)st, 64);
        if (lane >= st) x = fmaf(d, y, x);
        d = d * d;
    }
    float init = __shfl_up(x, 1u, 64);
    if (lane == 0) init = 0.f;
    // pass B: replay with true init, write outputs
    float acc = init;
#pragma unroll
    for (int j = 0; j < 32; ++j) {
        acc = fmaf(0.99f, acc, 0.01f * m[j]);
        const int t = lane * 32 + j;
        size_t ro = ((size_t)(b * T_ + t)) * KF_ + e * F_;
        Fcat[ro + 4] = f2bf(acc);
        Fcat[ro + 5] = f2bf(log1pf(acc));
    }
}

// ---------------- mag + bf16 frf/fif into Abig ----------------
__global__ __launch_bounds__(256) void k_mag(const float* __restrict__ FRF,
                                             unsigned short* __restrict__ Abig)
{
    const int gid = blockIdx.x * 256 + threadIdx.x;  // BT_*H_
    const int row = gid >> 10;
    const int h = gid & (H_ - 1);
    const float fr = FRF[(size_t)row * 2048 + h];
    const float fi = FRF[(size_t)row * 2048 + 1024 + h];
    const size_t base = (size_t)row * 4096;
    Abig[base + 1024 + h] = f2bf(fr);
    Abig[base + 2048 + h] = f2bf(fi);
    Abig[base + 3072 + h] = f2bf(sqrtf(fr * fr + fi * fi + 1e-6f));
}

// ---------------- final gate + combine ----------------
__global__ __launch_bounds__(256) void k_final(const float* __restrict__ preact,
                                               const float* __restrict__ gb,
                                               const float* __restrict__ FRF,
                                               const float* __restrict__ x,
                                               float* __restrict__ out)
{
    const int gid = blockIdx.x * 256 + threadIdx.x;  // BT_*H_
    const int h = gid & (H_ - 1);
    const int row = gid >> 10;
    const float z = preact[gid] + gb[h];
    const float g = 1.f / (1.f + __expf(-z));
    const float fr = FRF[(size_t)row * 2048 + h];
    out[gid] = g * fr + (1.f - g) * x[gid];
}

extern "C" void kernel_launch(void* const* d_in, const int* in_sizes, int n_in,
                              void* d_out, int out_size, void* d_ws, size_t ws_size,
                              hipStream_t stream)
{
    const float* x     = (const float*)d_in[0];
    const float* sigWr = (const float*)d_in[1];
    const float* sigWi = (const float*)d_in[2];
    const float* sigbr = (const float*)d_in[3];
    const float* sigbi = (const float*)d_in[4];
    const float* A_r   = (const float*)d_in[5];
    const float* A_i   = (const float*)d_in[6];
    const float* lam_r = (const float*)d_in[7];
    const float* lam_i = (const float*)d_in[8];
    const float* ehWr  = (const float*)d_in[9];
    const float* ehWi  = (const float*)d_in[10];
    const float* ehbr  = (const float*)d_in[11];
    const float* ehbi  = (const float*)d_in[12];
    const float* fuWr  = (const float*)d_in[13];
    const float* fuWi  = (const float*)d_in[14];
    const float* fubr  = (const float*)d_in[15];
    const float* fubi  = (const float*)d_in[16];
    const float* gW    = (const float*)d_in[17];
    const float* gb    = (const float*)d_in[18];

    char* ws = (char*)d_ws;
    size_t off = 0;
    auto alloc = [&](size_t bytes) -> void* {
        void* p = ws + off;
        off = (off + bytes + 255) & ~(size_t)255;
        return p;
    };
    unsigned short* Abig = (unsigned short*)alloc((size_t)BT_ * 4096 * 2);
    float* FRF           = (float*)alloc((size_t)BT_ * 2048 * 4);
    unsigned short* Fcat = (unsigned short*)alloc((size_t)BT_ * KF_ * 2);
    float* U             = (float*)alloc((size_t)BT_ * 128 * 4);
    float* Hr            = (float*)alloc((size_t)BT_ * 64 * 4);
    float* Hi            = (float*)alloc((size_t)BT_ * 64 * 4);
    float* Mbuf          = (float*)alloc((size_t)16 * T_ * 4);
    float* preact        = (float*)alloc((size_t)BT_ * H_ * 4);
    unsigned short* WuT  = (unsigned short*)alloc((size_t)128 * H_ * 2);
    float* b_u           = (float*)alloc(128 * 4);
    float* Mr            = (float*)alloc((size_t)152 * H_ * 4);
    float* Mi            = (float*)alloc((size_t)152 * H_ * 4);
    unsigned short* W2T  = (unsigned short*)alloc((size_t)2048 * KF_ * 2);
    float* b2            = (float*)alloc(2048 * 4);
    unsigned short* gWT  = (unsigned short*)alloc((size_t)H_ * 4096 * 2);
    if (off > ws_size) return;   // workspace too small; fail loudly (output stays poisoned)

    hipMemsetAsync(Fcat, 0, (size_t)BT_ * KF_ * 2, stream);
    hipMemsetAsync(Mr, 0, (size_t)2 * 152 * H_ * 4, stream);   // Mr and Mi contiguous

    k_cast_x<<<dim3(BT_ * H_ / 4 / 256), dim3(256), 0, stream>>>(x, Abig);
    k_gwt<<<dim3(128, 32), dim3(256), 0, stream>>>(gW, gWT);
    k_wu<<<dim3(H_), dim3(64), 0, stream>>>(sigWr, sigWi, A_r, A_i, WuT);
    k_bu<<<dim3(1), dim3(128), 0, stream>>>(sigbr, sigbi, A_r, A_i, b_u);
    k_b2init<<<dim3(8), dim3(256), 0, stream>>>(fubr, fubi, b2);
    k_mcompose<<<dim3(256), dim3(256), 0, stream>>>(ehWr, ehWi, ehbr, ehbi, fuWr, fuWi, Mr, Mi, b2);
    k_w2t<<<dim3(2048 * KF_ / 256), dim3(256), 0, stream>>>(Mr, Mi, W2T);

    // u = x @ WuT^T + b_u   [8192,1024]x[1024,128]
    k_gemm<<<dim3(1, 64), dim3(256), 0, stream>>>(Abig, 4096, WuT, H_, U, 128, b_u, H_);

    k_scan<<<dim3(B_ * 64), dim3(64), 0, stream>>>(U, lam_r, lam_i, Hr, Hi);
    k_feat<<<dim3(BT_ * E_ / 256), dim3(256), 0, stream>>>(Hr, Hi, Fcat, Mbuf);
    k_acc<<<dim3(4), dim3(256), 0, stream>>>(Mbuf, Fcat);

    // (frf|fif) = Fcat @ W2T^T + b2   [8192,320]x[320,2048]
    k_gemm<<<dim3(16, 64), dim3(256), 0, stream>>>(Fcat, KF_, W2T, KF_, FRF, 2048, b2, KF_);

    k_mag<<<dim3(BT_ * H_ / 256), dim3(256), 0, stream>>>(FRF, Abig);

    // preact = [x|frf|fif|mag] @ gWT^T   [8192,4096]x[4096,1024]
    k_gemm<<<dim3(8, 64), dim3(256), 0, stream>>>(Abig, 4096, gWT, 4096, preact, H_, (const float*)nullptr, 4096);

    k_final<<<dim3(BT_ * H_ / 256), dim3(256), 0, stream>>>(preact, gb, FRF, x, (float*)d_out);
}

// Round 3
// 354.368 us; speedup vs baseline: 4.0945x; 1.5469x over previous
//
#include <hip/hip_runtime.h>
#include <stdint.h>

#define B_ 4
#define T_ 2048
#define H_ 1024
#define S_ 512
#define R_ 16
#define E_ 4
#define F_ 38
#define BT_ (B_*T_)
#define KF_ 320   // padded 2*E*F = 304 -> 320

typedef __attribute__((ext_vector_type(8))) __bf16 bf16x8;
typedef __attribute__((ext_vector_type(4))) float f32x4;

static __device__ __forceinline__ unsigned short f2bf(float f) {
    unsigned int u = __float_as_uint(f);
    unsigned int r = (u + 0x7fffu + ((u >> 16) & 1u)) >> 16;
    return (unsigned short)r;
}

// ---------------- bf16 MFMA GEMM: C[M,N] (fp32) = A[M,K] @ BT[N,K]^T + bias ----------------
// 128x128 tile, 4 waves (2x2), each wave 64x64 = 4x4 MFMA 16x16x32 subtiles. K % 32 == 0.
// z-batched via strides (pass 0s for a single GEMM).
__global__ __launch_bounds__(256) void k_gemm(
    const unsigned short* __restrict__ A, int lda,
    const unsigned short* __restrict__ BT, int ldb,
    float* __restrict__ C, int ldc,
    const float* __restrict__ bias, int K,
    size_t sA, size_t sB, size_t sC)
{
    A  += (size_t)blockIdx.z * sA;
    BT += (size_t)blockIdx.z * sB;
    C  += (size_t)blockIdx.z * sC;
    __shared__ unsigned short As[128 * 32];
    __shared__ unsigned short Bs[128 * 32];
    const int tid = threadIdx.x;
    const int l = tid & 63;
    const int w = tid >> 6;
    const int wm = w >> 1, wn = w & 1;
    const int m16 = l & 15, kg = l >> 4;
    const size_t bm = (size_t)blockIdx.y * 128;
    const size_t bn = (size_t)blockIdx.x * 128;

    const int rS = tid >> 2;
    const int kS = (tid & 3) * 8;
    const unsigned short* pA0 = A + (bm + rS) * (size_t)lda + kS;
    const unsigned short* pA1 = pA0 + (size_t)64 * lda;
    const unsigned short* pB0 = BT + (bn + rS) * (size_t)ldb + kS;
    const unsigned short* pB1 = pB0 + (size_t)64 * ldb;

    f32x4 acc[4][4];
#pragma unroll
    for (int i = 0; i < 4; ++i)
#pragma unroll
        for (int j = 0; j < 4; ++j) acc[i][j] = (f32x4){0.f, 0.f, 0.f, 0.f};

    uint4 ra0 = *(const uint4*)pA0;
    uint4 ra1 = *(const uint4*)pA1;
    uint4 rb0 = *(const uint4*)pB0;
    uint4 rb1 = *(const uint4*)pB1;

    const int s0 = tid * 8;
    const int s1 = (256 + tid) * 8;
    const int nkt = K >> 5;
    for (int kt = 0; kt < nkt; ++kt) {
        __syncthreads();
        *(uint4*)&As[s0] = ra0;
        *(uint4*)&As[s1] = ra1;
        *(uint4*)&Bs[s0] = rb0;
        *(uint4*)&Bs[s1] = rb1;
        if (kt + 1 < nkt) {
            pA0 += 32; pA1 += 32; pB0 += 32; pB1 += 32;
            ra0 = *(const uint4*)pA0;
            ra1 = *(const uint4*)pA1;
            rb0 = *(const uint4*)pB0;
            rb1 = *(const uint4*)pB1;
        }
        __syncthreads();
        bf16x8 af[4], bfr[4];
#pragma unroll
        for (int i = 0; i < 4; ++i)
            af[i] = *(const bf16x8*)&As[(wm * 64 + i * 16 + m16) * 32 + kg * 8];
#pragma unroll
        for (int j = 0; j < 4; ++j)
            bfr[j] = *(const bf16x8*)&Bs[(wn * 64 + j * 16 + m16) * 32 + kg * 8];
#pragma unroll
        for (int i = 0; i < 4; ++i)
#pragma unroll
            for (int j = 0; j < 4; ++j)
                acc[i][j] = __builtin_amdgcn_mfma_f32_16x16x32_bf16(af[i], bfr[j], acc[i][j], 0, 0, 0);
    }

#pragma unroll
    for (int j = 0; j < 4; ++j) {
        const size_t col = bn + wn * 64 + j * 16 + m16;
        const float bv = bias ? bias[col] : 0.f;
#pragma unroll
        for (int i = 0; i < 4; ++i) {
            const size_t row0 = bm + wm * 64 + i * 16 + kg * 4;
#pragma unroll
            for (int p = 0; p < 4; ++p)
                C[(row0 + p) * (size_t)ldc + col] = acc[i][j][p] + bv;
        }
    }
}

// ---------------- cast x -> bf16 into Abig cols [0,1024) ----------------
__global__ __launch_bounds__(256) void k_cast_x(const float* __restrict__ x,
                                                unsigned short* __restrict__ Abig)
{
    const int gid = blockIdx.x * 256 + threadIdx.x;   // BT_*H_/4
    const int row = gid >> 8;
    const int c4 = (gid & 255) << 2;
    float4 v = *(const float4*)&x[(size_t)row * H_ + c4];
    ushort4 o;
    o.x = f2bf(v.x); o.y = f2bf(v.y); o.z = f2bf(v.z); o.w = f2bf(v.w);
    *(ushort4*)&Abig[(size_t)row * 4096 + c4] = o;
}

// ---------------- transpose-cast g_W [4096,1024] -> gWT bf16 [1024,4096] ----------------
__global__ __launch_bounds__(256) void k_gwt(const float* __restrict__ gW,
                                             unsigned short* __restrict__ gWT)
{
    __shared__ float tile[32][33];
    const int tx = threadIdx.x & 31, ty = threadIdx.x >> 5;   // ty 0..7
    const int k0 = blockIdx.x * 32, n0 = blockIdx.y * 32;
#pragma unroll
    for (int q = 0; q < 4; ++q) {
        int kk = ty * 4 + q;
        tile[kk][tx] = gW[(size_t)(k0 + kk) * H_ + n0 + tx];
    }
    __syncthreads();
#pragma unroll
    for (int q = 0; q < 4; ++q) {
        int nn = ty * 4 + q;
        gWT[(size_t)(n0 + nn) * 4096 + k0 + tx] = f2bf(tile[tx][nn]);
    }
}

// ---------------- WuT[n,h] = composed sigma->A weights, bf16 [128,1024] ----------------
__global__ __launch_bounds__(64) void k_wu(const float* __restrict__ sigWr,
                                           const float* __restrict__ sigWi,
                                           const float* __restrict__ A_r,
                                           const float* __restrict__ A_i,
                                           unsigned short* __restrict__ WuT)
{
    __shared__ float swr[S_], swi[S_];
    const int h = blockIdx.x;
    const int tid = threadIdx.x;
    for (int s = tid; s < S_; s += 64) {
        swr[s] = sigWr[(size_t)h * S_ + s];
        swi[s] = sigWi[(size_t)h * S_ + s];
    }
    __syncthreads();
    const int e = tid >> 4, r = tid & 15;
    float a0 = 0.f, a1 = 0.f;
    for (int s = 0; s < S_; ++s) {
        float ar = A_r[((size_t)(e * S_ + s)) * R_ + r];
        float ai = A_i[((size_t)(e * S_ + s)) * R_ + r];
        float wr = swr[s], wi = swi[s];
        a0 += wr * ar - wi * ai;
        a1 += wr * ai + wi * ar;
    }
    WuT[(size_t)tid * H_ + h] = f2bf(a0);
    WuT[(size_t)(64 + tid) * H_ + h] = f2bf(a1);
}

// ---------------- b_u[128]: 128 blocks, wave-reduce over s ----------------
__global__ __launch_bounds__(64) void k_bu(const float* __restrict__ sigbr,
                                           const float* __restrict__ sigbi,
                                           const float* __restrict__ A_r,
                                           const float* __restrict__ A_i,
                                           float* __restrict__ b_u)
{
    const int n = blockIdx.x;                 // 0..127
    const int lane = threadIdx.x;
    const int m = n & 63;
    const int e = m >> 4, r = m & 15;
    const bool hi = n >= 64;
    float acc = 0.f;
    for (int s = lane; s < S_; s += 64) {
        float ar = A_r[((size_t)(e * S_ + s)) * R_ + r];
        float ai = A_i[((size_t)(e * S_ + s)) * R_ + r];
        float br = sigbr[s], bi = sigbi[s];
        acc += hi ? (br * ai + bi * ar) : (br * ar - bi * ai);
    }
#pragma unroll
    for (int st = 32; st; st >>= 1) acc += __shfl_down(acc, st, 64);
    if (lane == 0) b_u[n] = acc;
}

// ---------------- build Acomp bf16 [4][128][2048]: rows 0..37=[ehWr|ehWi], 38=[ehbr|ehbi], rest 0 ----------------
__global__ __launch_bounds__(256) void k_prepA(const float* __restrict__ ehWr,
                                               const float* __restrict__ ehWi,
                                               const float* __restrict__ ehbr,
                                               const float* __restrict__ ehbi,
                                               unsigned short* __restrict__ Ac)
{
    const int gid = blockIdx.x * 256 + threadIdx.x;  // 262144 groups of 4
    const int e = gid >> 16;
    const int rem = gid & 65535;
    const int row = rem >> 9;
    const int k = (rem & 511) << 2;
    float4 f = {0.f, 0.f, 0.f, 0.f};
    if (row < F_) {
        const float* src = (k < 1024) ? ehWr + ((size_t)(e * F_ + row)) * 1024 + k
                                      : ehWi + ((size_t)(e * F_ + row)) * 1024 + (k - 1024);
        f = *(const float4*)src;
    } else if (row == F_) {
        const float* src = (k < 1024) ? ehbr + (size_t)e * 1024 + k
                                      : ehbi + (size_t)e * 1024 + (k - 1024);
        f = *(const float4*)src;
    }
    ushort4 o;
    o.x = f2bf(f.x); o.y = f2bf(f.y); o.z = f2bf(f.z); o.w = f2bf(f.w);
    *(ushort4*)&Ac[(size_t)gid * 4] = o;
}

// ---------------- build Bcomp bf16 [4][2048][2048] = [[fuWr|fuWi],[-fuWi|fuWr]]^T-per-engine ----------------
// Bcomp[e][n][k] with n=h (top) / 1024+h (bottom); transpose of fuW's [k,h] layout via LDS tile.
__global__ __launch_bounds__(256) void k_prepB(const float* __restrict__ fuWr,
                                               const float* __restrict__ fuWi,
                                               unsigned short* __restrict__ Bc)
{
    __shared__ float tR[32][33], tI[32][33];
    const int e = blockIdx.z;
    const int k0 = blockIdx.x * 32;   // contraction index block (fu row)
    const int h0 = blockIdx.y * 32;   // output h block (fu col)
    const int tx = threadIdx.x & 31, ty = threadIdx.x >> 5;
    const float* fr = fuWr + ((size_t)e * 1024 + k0) * 1024 + h0;
    const float* fi = fuWi + ((size_t)e * 1024 + k0) * 1024 + h0;
#pragma unroll
    for (int q = 0; q < 4; ++q) {
        int kk = ty * 4 + q;
        tR[kk][tx] = fr[(size_t)kk * 1024 + tx];
        tI[kk][tx] = fi[(size_t)kk * 1024 + tx];
    }
    __syncthreads();
    unsigned short* Be = Bc + (size_t)e * 2048 * 2048;
#pragma unroll
    for (int q = 0; q < 4; ++q) {
        int rr = ty * 4 + q;
        float vR = tR[tx][rr], vI = tI[tx][rr];
        size_t rowLo = (size_t)(h0 + rr) * 2048;
        size_t rowHi = (size_t)(1024 + h0 + rr) * 2048;
        Be[rowLo + k0 + tx]        = f2bf(vR);
        Be[rowLo + 1024 + k0 + tx] = f2bf(-vI);
        Be[rowHi + k0 + tx]        = f2bf(vI);
        Be[rowHi + 1024 + k0 + tx] = f2bf(vR);
    }
}

// ---------------- pack W2T bf16 [2048, KF_] from composed C [4][128][2048] ----------------
__global__ __launch_bounds__(256) void k_w2t(const float* __restrict__ C,
                                             unsigned short* __restrict__ W2T)
{
    const int gid = blockIdx.x * 256 + threadIdx.x;  // 2048*KF_
    const int n = gid / KF_;
    const int k = gid - n * KF_;
    const int h = n & (H_ - 1);
    const bool hiRow = n >= H_;
    float v = 0.f;
    if (k < 304) {
        const int fp = (k < 152) ? k : k - 152;
        const int e = fp / F_;
        const int f = fp - e * F_;
        const float* Ce = C + ((size_t)e * 128 + f) * 2048;
        const float mr = Ce[h], mi = Ce[1024 + h];
        if (!hiRow) v = (k < 152) ? mr : -mi;
        else        v = (k < 152) ? mi :  mr;
    }
    W2T[gid] = f2bf(v);
}

// ---------------- b2[2048] = fu_b + sum_e C[e][38][:] ----------------
__global__ __launch_bounds__(256) void k_b2(const float* __restrict__ fubr,
                                            const float* __restrict__ fubi,
                                            const float* __restrict__ C,
                                            float* __restrict__ b2)
{
    const int n = blockIdx.x * 256 + threadIdx.x;   // 2048
    float v = (n < H_) ? fubr[n] : fubi[n - H_];
#pragma unroll
    for (int e = 0; e < 4; ++e)
        v += C[(size_t)e * 128 * 2048 + (size_t)F_ * 2048 + n];
    b2[n] = v;
}

// ---------------- chunk-parallel complex recurrence: one wave per (b,channel) ----------------
__global__ __launch_bounds__(64) void k_scan(const float* __restrict__ U,
                                             const float* __restrict__ lam_r,
                                             const float* __restrict__ lam_i,
                                             float* __restrict__ Hr, float* __restrict__ Hi)
{
    const int wid = blockIdx.x;              // 256 = b*64 + ch
    const int b = wid >> 6, ch = wid & 63;
    const int lane = threadIdx.x;
    const float cr = 0.9f * lam_r[ch];
    const float ci = 0.9f * lam_i[ch];
    const float* Ub = U + (size_t)b * T_ * 128;
    const int t0 = lane * 32;
    float ur[32], ui[32];
#pragma unroll
    for (int j = 0; j < 32; ++j) {
        ur[j] = Ub[(size_t)(t0 + j) * 128 + ch];
        ui[j] = Ub[(size_t)(t0 + j) * 128 + 64 + ch];
    }
    float hr = 0.f, hi = 0.f;
#pragma unroll
    for (int j = 0; j < 32; ++j) {
        float nr = fmaf(cr, hr, fmaf(-ci, hi, 0.1f * ur[j]));
        float ni = fmaf(cr, hi, fmaf(ci, hr, 0.1f * ui[j]));
        hr = nr; hi = ni;
    }
    float dr = cr, di = ci;
#pragma unroll
    for (int q = 0; q < 5; ++q) { float t = dr*dr - di*di; di = 2.f*dr*di; dr = t; }
    float xr = hr, xi = hi;
#pragma unroll
    for (int st = 1; st < 64; st <<= 1) {
        float yr = __shfl_up(xr, (unsigned)st, 64);
        float yi = __shfl_up(xi, (unsigned)st, 64);
        if (lane >= st) {
            float nxr = fmaf(dr, yr, fmaf(-di, yi, xr));
            float nxi = fmaf(dr, yi, fmaf(di, yr, xi));
            xr = nxr; xi = nxi;
        }
        float t = dr*dr - di*di; di = 2.f*dr*di; dr = t;
    }
    float ir = __shfl_up(xr, 1u, 64);
    float ii = __shfl_up(xi, 1u, 64);
    if (lane == 0) { ir = 0.f; ii = 0.f; }
    hr = ir; hi = ii;
    float* HrB = Hr + (size_t)b * T_ * 64;
    float* HiB = Hi + (size_t)b * T_ * 64;
#pragma unroll
    for (int j = 0; j < 32; ++j) {
        float nr = fmaf(cr, hr, fmaf(-ci, hi, 0.1f * ur[j]));
        float ni = fmaf(cr, hi, fmaf(ci, hr, 0.1f * ui[j]));
        HrB[(size_t)(t0 + j) * 64 + ch] = nr;
        HiB[(size_t)(t0 + j) * 64 + ch] = ni;
        hr = nr; hi = ni;
    }
}

// ---------------- per-(e,b,t) features (parallel) ----------------
__global__ __launch_bounds__(256) void k_feat(const float* __restrict__ Hr,
                                              const float* __restrict__ Hi,
                                              unsigned short* __restrict__ Fcat,
                                              float* __restrict__ Mbuf)
{
    const int gid = blockIdx.x * 256 + threadIdx.x;  // 32768
    const int e = gid & 3;
    const int bt = gid >> 2;
    const float* hr = Hr + (size_t)bt * 64 + e * 16;
    const float* hi = Hi + (size_t)bt * 64 + e * 16;
    float nr[16], ni[16];
#pragma unroll
    for (int q = 0; q < 4; ++q) {
        float4 vr = ((const float4*)hr)[q];
        float4 vi = ((const float4*)hi)[q];
        nr[q*4+0]=vr.x; nr[q*4+1]=vr.y; nr[q*4+2]=vr.z; nr[q*4+3]=vr.w;
        ni[q*4+0]=vi.x; ni[q*4+1]=vi.y; ni[q*4+2]=vi.z; ni[q*4+3]=vi.w;
    }
    float sum = 0.f, mx = 0.f, sr = 0.f, si = 0.f;
#pragma unroll
    for (int i = 0; i < 16; ++i) {
        float m2 = nr[i] * nr[i] + ni[i] * ni[i];
        sum += m2; mx = fmaxf(mx, m2);
        sr += nr[i]; si += ni[i];
    }
    const float mm = sum * 0.0625f;
    const float inv = rsqrtf(mm + 1e-6f);
    const int b = bt >> 11, t = bt & (T_ - 1);
    Mbuf[(size_t)(e * 4 + b) * T_ + t] = mm;
    unsigned short* Fp = Fcat + (size_t)bt * KF_;
    const int br = e * F_, bi2 = 152 + e * F_;
    const float mhr = sr * 0.0625f * inv;
    const float mhi = si * 0.0625f * inv;
    Fp[br + 0] = f2bf(mhr);
    Fp[br + 1] = f2bf(mhi);
    Fp[br + 2] = f2bf(sqrtf(mm + 1e-6f));
    Fp[br + 3] = f2bf(sqrtf(mx + 1e-6f));
    Fp[bi2 + 0] = f2bf(mhi);
    Fp[bi2 + 1] = f2bf(-mhr);
#pragma unroll
    for (int i = 0; i < 16; ++i) {
        float a = nr[i] * inv, c = ni[i] * inv;
        Fp[br + 6 + i]   = f2bf(a);
        Fp[br + 22 + i]  = f2bf(c);
        Fp[bi2 + 6 + i]  = f2bf(c);
        Fp[bi2 + 22 + i] = f2bf(-a);
    }
}

// ---------------- acc recurrence: 16 waves, chunk-parallel affine scan ----------------
__global__ __launch_bounds__(256) void k_acc(const float* __restrict__ Mbuf,
                                             unsigned short* __restrict__ Fcat)
{
    const int w = blockIdx.x * 4 + (threadIdx.x >> 6);   // 16 sequences
    const int lane = threadIdx.x & 63;
    const int e = w >> 2, b = w & 3;
    const float* mp = Mbuf + (size_t)(e * 4 + b) * T_ + lane * 32;
    float m[32];
#pragma unroll
    for (int j = 0; j < 32; ++j) m[j] = mp[j];
    float s = 0.f;
#pragma unroll
    for (int j = 0; j < 32; ++j) s = fmaf(0.99f, s, 0.01f * m[j]);
    float d = 0.99f;
#pragma unroll
    for (int q = 0; q < 5; ++q) d = d * d;
    float x = s;
#pragma unroll
    for (int st = 1; st < 64; st <<= 1) {
        float y = __shfl_up(x, (unsigned)st, 64);
        if (lane >= st) x = fmaf(d, y, x);
        d = d * d;
    }
    float init = __shfl_up(x, 1u, 64);
    if (lane == 0) init = 0.f;
    float acc = init;
#pragma unroll
    for (int j = 0; j < 32; ++j) {
        acc = fmaf(0.99f, acc, 0.01f * m[j]);
        const int t = lane * 32 + j;
        size_t ro = ((size_t)(b * T_ + t)) * KF_ + e * F_;
        Fcat[ro + 4] = f2bf(acc);
        Fcat[ro + 5] = f2bf(log1pf(acc));
    }
}

// ---------------- mag + bf16 frf/fif into Abig ----------------
__global__ __launch_bounds__(256) void k_mag(const float* __restrict__ FRF,
                                             unsigned short* __restrict__ Abig)
{
    const int gid = blockIdx.x * 256 + threadIdx.x;  // BT_*H_
    const int row = gid >> 10;
    const int h = gid & (H_ - 1);
    const float fr = FRF[(size_t)row * 2048 + h];
    const float fi = FRF[(size_t)row * 2048 + 1024 + h];
    const size_t base = (size_t)row * 4096;
    Abig[base + 1024 + h] = f2bf(fr);
    Abig[base + 2048 + h] = f2bf(fi);
    Abig[base + 3072 + h] = f2bf(sqrtf(fr * fr + fi * fi + 1e-6f));
}

// ---------------- final gate + combine ----------------
__global__ __launch_bounds__(256) void k_final(const float* __restrict__ preact,
                                               const float* __restrict__ gb,
                                               const float* __restrict__ FRF,
                                               const float* __restrict__ x,
                                               float* __restrict__ out)
{
    const int gid = blockIdx.x * 256 + threadIdx.x;  // BT_*H_
    const int h = gid & (H_ - 1);
    const int row = gid >> 10;
    const float z = preact[gid] + gb[h];
    const float g = 1.f / (1.f + __expf(-z));
    const float fr = FRF[(size_t)row * 2048 + h];
    out[gid] = g * fr + (1.f - g) * x[gid];
}

extern "C" void kernel_launch(void* const* d_in, const int* in_sizes, int n_in,
                              void* d_out, int out_size, void* d_ws, size_t ws_size,
                              hipStream_t stream)
{
    const float* x     = (const float*)d_in[0];
    const float* sigWr = (const float*)d_in[1];
    const float* sigWi = (const float*)d_in[2];
    const float* sigbr = (const float*)d_in[3];
    const float* sigbi = (const float*)d_in[4];
    const float* A_r   = (const float*)d_in[5];
    const float* A_i   = (const float*)d_in[6];
    const float* lam_r = (const float*)d_in[7];
    const float* lam_i = (const float*)d_in[8];
    const float* ehWr  = (const float*)d_in[9];
    const float* ehWi  = (const float*)d_in[10];
    const float* ehbr  = (const float*)d_in[11];
    const float* ehbi  = (const float*)d_in[12];
    const float* fuWr  = (const float*)d_in[13];
    const float* fuWi  = (const float*)d_in[14];
    const float* fubr  = (const float*)d_in[15];
    const float* fubi  = (const float*)d_in[16];
    const float* gW    = (const float*)d_in[17];
    const float* gb    = (const float*)d_in[18];

    char* ws = (char*)d_ws;
    size_t off = 0;
    auto alloc = [&](size_t bytes) -> void* {
        void* p = ws + off;
        off = (off + bytes + 255) & ~(size_t)255;
        return p;
    };
    unsigned short* Abig = (unsigned short*)alloc((size_t)BT_ * 4096 * 2);
    float* FRF           = (float*)alloc((size_t)BT_ * 2048 * 4);
    unsigned short* Fcat = (unsigned short*)alloc((size_t)BT_ * KF_ * 2);
    float* U             = (float*)alloc((size_t)BT_ * 128 * 4);
    float* Hr            = (float*)alloc((size_t)BT_ * 64 * 4);
    float* Hi            = (float*)alloc((size_t)BT_ * 64 * 4);
    float* Mbuf          = (float*)alloc((size_t)16 * T_ * 4);
    float* preact        = (float*)alloc((size_t)BT_ * H_ * 4);
    unsigned short* WuT  = (unsigned short*)alloc((size_t)128 * H_ * 2);
    float* b_u           = (float*)alloc(128 * 4);
    unsigned short* W2T  = (unsigned short*)alloc((size_t)2048 * KF_ * 2);
    float* b2            = (float*)alloc(2048 * 4);
    unsigned short* gWT  = (unsigned short*)alloc((size_t)H_ * 4096 * 2);
    unsigned short* Acomp= (unsigned short*)alloc((size_t)4 * 128 * 2048 * 2);
    // Aliases: Bcomp lives in FRF's slot (FRF written later); Ccomp in preact's slot.
    unsigned short* Bcomp = (unsigned short*)FRF;     // 4*2048*2048*2 = 33.5 MB <= 67 MB
    float* Ccomp          = (float*)preact;           // 4*128*2048*4  =  4 MB  <= 33.5 MB
    if (off > ws_size) return;   // workspace too small; fail loudly (output stays poisoned)

    hipMemsetAsync(Fcat, 0, (size_t)BT_ * KF_ * 2, stream);

    k_cast_x<<<dim3(BT_ * H_ / 4 / 256), dim3(256), 0, stream>>>(x, Abig);
    k_gwt<<<dim3(128, 32), dim3(256), 0, stream>>>(gW, gWT);
    k_wu<<<dim3(H_), dim3(64), 0, stream>>>(sigWr, sigWi, A_r, A_i, WuT);
    k_bu<<<dim3(128), dim3(64), 0, stream>>>(sigbr, sigbi, A_r, A_i, b_u);
    k_prepA<<<dim3(1024), dim3(256), 0, stream>>>(ehWr, ehWi, ehbr, ehbi, Acomp);
    k_prepB<<<dim3(32, 32, 4), dim3(256), 0, stream>>>(fuWr, fuWi, Bcomp);

    // M composition: per-engine [128,2048] x [2048,2048] -> Ccomp [4][128][2048]
    k_gemm<<<dim3(16, 1, 4), dim3(256), 0, stream>>>(
        Acomp, 2048, Bcomp, 2048, Ccomp, 2048, (const float*)nullptr, 2048,
        (size_t)128 * 2048, (size_t)2048 * 2048, (size_t)128 * 2048);

    k_w2t<<<dim3(2048 * KF_ / 256), dim3(256), 0, stream>>>(Ccomp, W2T);
    k_b2<<<dim3(8), dim3(256), 0, stream>>>(fubr, fubi, Ccomp, b2);

    // u = x @ WuT^T + b_u   [8192,1024]x[1024,128]
    k_gemm<<<dim3(1, 64), dim3(256), 0, stream>>>(Abig, 4096, WuT, H_, U, 128, b_u, H_, 0, 0, 0);

    k_scan<<<dim3(B_ * 64), dim3(64), 0, stream>>>(U, lam_r, lam_i, Hr, Hi);
    k_feat<<<dim3(BT_ * E_ / 256), dim3(256), 0, stream>>>(Hr, Hi, Fcat, Mbuf);
    k_acc<<<dim3(4), dim3(256), 0, stream>>>(Mbuf, Fcat);

    // (frf|fif) = Fcat @ W2T^T + b2   [8192,320]x[320,2048]
    k_gemm<<<dim3(16, 64), dim3(256), 0, stream>>>(Fcat, KF_, W2T, KF_, FRF, 2048, b2, KF_, 0, 0, 0);

    k_mag<<<dim3(BT_ * H_ / 256), dim3(256), 0, stream>>>(FRF, Abig);

    // preact = [x|frf|fif|mag] @ gWT^T   [8192,4096]x[4096,1024]
    k_gemm<<<dim3(8, 64), dim3(256), 0, stream>>>(Abig, 4096, gWT, 4096, preact, H_, (const float*)nullptr, 4096, 0, 0, 0);

    k_final<<<dim3(BT_ * H_ / 256), dim3(256), 0, stream>>>(preact, gb, FRF, x, (float*)d_out);
}